// Round 1
// baseline (324.557 us; speedup 1.0000x reference)
//
#include <hip/hip_runtime.h>

#pragma clang fp contract(off)

#define NBOX 262144
#define NCLS 80
#define ROWS 85
#define CAP 1024
#define POOL 8192

// ---------------- init: zero atomic counters (ws is poisoned 0xAA each call)
__global__ __launch_bounds__(128) void k_init(int* __restrict__ cls_count,
                                              int* __restrict__ pool_count) {
    int t = threadIdx.x;
    if (t < NCLS) cls_count[t] = 0;
    if (t == NCLS) *pool_count = 0;
}

// ---------------- stage1: classify + compact valid boxes into per-class lists
__global__ __launch_bounds__(256) void k_stage1(const float* __restrict__ det,
                                                float* __restrict__ cls_score,
                                                int* __restrict__ cls_idx,
                                                float* __restrict__ cls_conf,
                                                float4* __restrict__ cls_box,
                                                int* __restrict__ cls_count) {
    int i = blockIdx.x * 256 + threadIdx.x;
    if (i >= NBOX) return;
    const float* p = det + (long long)i * ROWS;
    float obj = p[4];
    if (!(obj >= 0.8f)) return;  // CONF_THRES
    float mx = p[5];
    int am = 0;
    #pragma unroll 4
    for (int j = 1; j < NCLS; j++) {
        float v = p[5 + j];
        if (v > mx) { mx = v; am = j; }  // strict > keeps first occurrence (jnp.argmax)
    }
    float x = p[0], y = p[1], w = p[2], h = p[3];
    float hw = w * 0.5f, hh = h * 0.5f;  // exact (mul by 0.5)
    float score = obj * mx;
    int pos = atomicAdd(&cls_count[am], 1);
    if (pos < CAP) {
        int o = am * CAP + pos;
        cls_score[o] = score;
        cls_idx[o] = i;
        cls_conf[o] = mx;
        cls_box[o] = make_float4(x - hw, y - hh, x + hw, y + hh);
    }
}

// ---------------- stage2+3: per-class sort (score desc, idx asc) + greedy NMS
__global__ __launch_bounds__(256) void k_nms(const float* __restrict__ cls_score,
                                             const int* __restrict__ cls_idx,
                                             const float* __restrict__ cls_conf,
                                             const float4* __restrict__ cls_box,
                                             const int* __restrict__ cls_count,
                                             unsigned long long* __restrict__ pool_key,
                                             float* __restrict__ pool_conf,
                                             int* __restrict__ pool_cls,
                                             int* __restrict__ pool_count) {
    __shared__ unsigned long long key[CAP];   // (~score_bits)<<32 | orig_idx
    __shared__ unsigned short slot[CAP];
    __shared__ float4 bx[CAP];
    __shared__ float cf[CAP];
    __shared__ unsigned char alive[CAP];
    const int c = blockIdx.x;
    const int t = threadIdx.x;
    const int n = min(cls_count[c], CAP);

    for (int p = t; p < CAP; p += 256) {
        if (p < n) {
            unsigned sb = __float_as_uint(cls_score[c * CAP + p]);  // score >= 0
            key[p] = ((unsigned long long)(~sb) << 32) | (unsigned)cls_idx[c * CAP + p];
        } else {
            key[p] = ~0ULL;
        }
        slot[p] = (unsigned short)p;
    }
    __syncthreads();

    // bitonic sort ascending: score desc, ties orig-idx asc (matches stable argsort)
    for (int k = 2; k <= CAP; k <<= 1) {
        for (int j = k >> 1; j > 0; j >>= 1) {
            for (int i = t; i < CAP; i += 256) {
                int ixj = i ^ j;
                if (ixj > i) {
                    unsigned long long a = key[i], b = key[ixj];
                    if ((a > b) == ((i & k) == 0)) {
                        key[i] = b; key[ixj] = a;
                        unsigned short s = slot[i]; slot[i] = slot[ixj]; slot[ixj] = s;
                    }
                }
            }
            __syncthreads();
        }
    }

    // gather payload in sorted order
    for (int p = t; p < n; p += 256) {
        int s = slot[p];
        bx[p] = cls_box[c * CAP + s];
        cf[p] = cls_conf[c * CAP + s];
        alive[p] = 1;
    }
    __syncthreads();

    // greedy NMS: sequential over picks, parallel IoU pass
    for (int i = 0; i < n; i++) {
        if (alive[i]) {  // uniform branch (broadcast LDS read)
            float4 cur = bx[i];
            float a1 = (cur.z - cur.x + 1.0f) * (cur.w - cur.y + 1.0f);
            for (int j = i + 1 + t; j < n; j += 256) {
                if (alive[j]) {
                    float4 b = bx[j];
                    float xx1 = fmaxf(cur.x, b.x);
                    float yy1 = fmaxf(cur.y, b.y);
                    float xx2 = fminf(cur.z, b.z);
                    float yy2 = fminf(cur.w, b.w);
                    float iw = xx2 - xx1 + 1.0f;
                    float ih = yy2 - yy1 + 1.0f;
                    float inter = fmaxf(iw, 0.0f) * fmaxf(ih, 0.0f);
                    float a2 = (b.z - b.x + 1.0f) * (b.w - b.y + 1.0f);
                    float iou = inter / (a1 + a2 - inter + 1e-16f);
                    if (iou > 0.4f) alive[j] = 0;  // NMS_THRES
                }
            }
            if (t == 0) {
                int pp = atomicAdd(pool_count, 1);
                if (pp < POOL) {
                    unsigned long long lk = key[i];
                    // repack: (~score)<<31 | orig_idx(18b)<<13 | pool_idx(13b)
                    pool_key[pp] = ((lk >> 32) << 31) | ((lk & 0xFFFFFFFFull) << 13) |
                                   (unsigned long long)pp;
                    pool_conf[pp] = cf[i];
                    pool_cls[pp] = c;
                }
            }
            __syncthreads();
        }
    }
}

// ---------------- stage4: global top-300 by score-key, then conf re-sort, output
__global__ __launch_bounds__(1024) void k_final(const unsigned long long* __restrict__ pool_key,
                                                const float* __restrict__ pool_conf,
                                                const int* __restrict__ pool_cls,
                                                const int* __restrict__ pool_count,
                                                float* __restrict__ out) {
    __shared__ unsigned long long skey[POOL];  // 64 KB
    const int t = threadIdx.x;
    const int K = min(*pool_count, POOL);
    for (int i = t; i < POOL; i += 1024) skey[i] = (i < K) ? pool_key[i] : ~0ULL;
    __syncthreads();

    int P = 512;
    while (P < K) P <<= 1;  // runtime-sized bitonic, P >= 512 > 300
    for (int k = 2; k <= P; k <<= 1) {
        for (int j = k >> 1; j > 0; j >>= 1) {
            for (int i = t; i < P; i += 1024) {
                int ixj = i ^ j;
                if (ixj > i) {
                    unsigned long long a = skey[i], b = skey[ixj];
                    if ((a > b) == ((i & k) == 0)) { skey[i] = b; skey[ixj] = a; }
                }
            }
            __syncthreads();
        }
    }

    // slot s = s-th global pick. Final order: conf desc, ties slot desc
    // (= reversed stable ascending argsort of the reference)
    const int M = min(K, 300);
    unsigned long long k2 = ~0ULL;
    unsigned cb = 0;
    int mycls = 0;
    if (t < M) {
        int pidx = (int)(skey[t] & 0x1FFFull);
        float cfv = pool_conf[pidx];
        mycls = pool_cls[pidx];
        cb = __float_as_uint(cfv);
        k2 = ((unsigned long long)(~cb) << 32) | (unsigned)(~t);
    }
    __syncthreads();
    if (t < 512) skey[t] = k2;  // t in [M,512) pads with ~0ULL
    if (t < M) {
        skey[1024 + t] = cb;
        skey[2048 + t] = (unsigned long long)(unsigned)mycls;
    }
    __syncthreads();
    for (int k = 2; k <= 512; k <<= 1) {
        for (int j = k >> 1; j > 0; j >>= 1) {
            for (int i = t; i < 512; i += 1024) {
                int ixj = i ^ j;
                if (ixj > i) {
                    unsigned long long a = skey[i], b = skey[ixj];
                    if ((a > b) == ((i & k) == 0)) { skey[i] = b; skey[ixj] = a; }
                }
            }
            __syncthreads();
        }
    }

    if (t < 300) {
        float idv = 0.0f, pv = 0.0f;
        if (t < M) {  // all valid keys sort before ~0ULL padding
            unsigned long long kk = skey[t];
            int slotv = (int)(~(unsigned)(kk & 0xFFFFFFFFull));
            pv = __uint_as_float((unsigned)skey[1024 + slotv]);
            idv = (float)(int)skey[2048 + slotv];
        }
        out[t] = idv;        // ids (1,300)
        out[300 + t] = pv;   // probs (300,)
    }
}

extern "C" void kernel_launch(void* const* d_in, const int* in_sizes, int n_in,
                              void* d_out, int out_size, void* d_ws, size_t ws_size,
                              hipStream_t stream) {
    const float* det = (const float*)d_in[0];
    float* out = (float*)d_out;
    char* ws = (char*)d_ws;

    // workspace layout (~2.4 MB total)
    int* cls_count = (int*)(ws);                      // 80 * 4
    int* pool_count = (int*)(ws + 384);               // 4
    float* cls_score = (float*)(ws + 512);            // 80*1024*4 = 327680
    int* cls_idx = (int*)(ws + 512 + 327680);         // 327680
    float* cls_conf = (float*)(ws + 512 + 655360);    // 327680
    float4* cls_box = (float4*)(ws + 983552);         // 80*1024*16 = 1310720 (16B aligned)
    unsigned long long* pool_key = (unsigned long long*)(ws + 2294272);  // 8192*8
    float* pool_conf = (float*)(ws + 2359808);        // 8192*4
    int* pool_cls = (int*)(ws + 2392576);             // 8192*4

    k_init<<<1, 128, 0, stream>>>(cls_count, pool_count);
    k_stage1<<<NBOX / 256, 256, 0, stream>>>(det, cls_score, cls_idx, cls_conf,
                                             cls_box, cls_count);
    k_nms<<<NCLS, 256, 0, stream>>>(cls_score, cls_idx, cls_conf, cls_box, cls_count,
                                    pool_key, pool_conf, pool_cls, pool_count);
    k_final<<<1, 1024, 0, stream>>>(pool_key, pool_conf, pool_cls, pool_count, out);
}

// Round 2
// 274.663 us; speedup vs baseline: 1.1817x; 1.1817x over previous
//
#include <hip/hip_runtime.h>

#pragma clang fp contract(off)

#define NBOX 262144
#define NCLS 80
#define ROWS 85
#define CAP 1024
#define POOL 8192
#define TBOX 128   // boxes per stage1 block

// ---------------- init: zero atomic counters (ws is poisoned 0xAA each call)
__global__ __launch_bounds__(128) void k_init(int* __restrict__ cls_count,
                                              int* __restrict__ pool_count) {
    int t = threadIdx.x;
    if (t < NCLS) cls_count[t] = 0;
    if (t == NCLS) *pool_count = 0;
}

// ---------------- stage1: coalesced LDS staging + classify + compact
__global__ __launch_bounds__(256) void k_stage1(const float4* __restrict__ det4,
                                                float* __restrict__ cls_score,
                                                int* __restrict__ cls_idx,
                                                float* __restrict__ cls_conf,
                                                float4* __restrict__ cls_box,
                                                int* __restrict__ cls_count) {
    __shared__ float4 s4[TBOX * ROWS / 4];   // 43,520 B, 16B-aligned
    float* s = (float*)s4;
    const int t = threadIdx.x;
    const int base4 = blockIdx.x * (TBOX * ROWS / 4);   // 2720 float4 per tile

    // coalesced 16B/lane staging of the whole contiguous tile
    for (int i = t; i < TBOX * ROWS / 4; i += 256) s4[i] = det4[base4 + i];
    __syncthreads();

    const int b = t >> 1, sub = t & 1;
    const float* p = s + b * ROWS;
    // each sub-thread scans 40 classes; stride-85 LDS reads = 2-way bank alias (free)
    const int cbase = 5 + sub * 40;
    float mx = p[cbase];
    int am = sub * 40;
    #pragma unroll 8
    for (int j = 1; j < 40; j++) {
        float v = p[cbase + j];
        if (v > mx) { mx = v; am = sub * 40 + j; }   // strict > = first occurrence
    }
    float omx = __shfl_xor(mx, 1);
    int oam = __shfl_xor(am, 1);
    if (sub == 0) {
        // sub1 holds higher class indices: take only on strict >
        if (omx > mx) { mx = omx; am = oam; }
        float obj = p[4];
        if (obj >= 0.8f) {   // CONF_THRES
            float x = p[0], y = p[1], w = p[2], h = p[3];
            float hw = w * 0.5f, hh = h * 0.5f;
            float score = obj * mx;
            int gi = blockIdx.x * TBOX + b;
            int pos = atomicAdd(&cls_count[am], 1);
            if (pos < CAP) {
                int o = am * CAP + pos;
                cls_score[o] = score;
                cls_idx[o] = gi;
                cls_conf[o] = mx;
                cls_box[o] = make_float4(x - hw, y - hh, x + hw, y + hh);
            }
        }
    }
}

// ---------------- stage2+3: per-class sort (score desc, idx asc) + greedy NMS
__global__ __launch_bounds__(1024) void k_nms(const float* __restrict__ cls_score,
                                              const int* __restrict__ cls_idx,
                                              const float* __restrict__ cls_conf,
                                              const float4* __restrict__ cls_box,
                                              const int* __restrict__ cls_count,
                                              unsigned long long* __restrict__ pool_key,
                                              float* __restrict__ pool_conf,
                                              int* __restrict__ pool_cls,
                                              int* __restrict__ pool_count) {
    __shared__ unsigned long long key[CAP];   // (~score_bits)<<32 | orig_idx
    __shared__ unsigned short slot[CAP];
    __shared__ float4 bx[CAP];
    __shared__ float cf[CAP];
    __shared__ unsigned words[CAP / 32];      // alive bitmask
    __shared__ int s_cur;
    const int c = blockIdx.x;
    const int t = threadIdx.x;
    const int n = min(cls_count[c], CAP);

    if (t < n) {
        unsigned sb = __float_as_uint(cls_score[c * CAP + t]);  // score >= 0
        key[t] = ((unsigned long long)(~sb) << 32) | (unsigned)cls_idx[c * CAP + t];
    } else {
        key[t] = ~0ULL;
    }
    slot[t] = (unsigned short)t;
    // alive bitmask init: bit p set iff p < n
    if (t < CAP / 32) {
        int lo = t << 5;
        words[t] = (n >= lo + 32) ? 0xFFFFFFFFu
                                  : (n > lo ? ((1u << (n - lo)) - 1u) : 0u);
    }
    __syncthreads();

    // bitonic sort ascending: score desc, ties orig-idx asc (stable-argsort match)
    for (int k = 2; k <= CAP; k <<= 1) {
        for (int j = k >> 1; j > 0; j >>= 1) {
            int ixj = t ^ j;
            if (ixj > t) {
                unsigned long long a = key[t], b = key[ixj];
                if ((a > b) == ((t & k) == 0)) {
                    key[t] = b; key[ixj] = a;
                    unsigned short sv = slot[t]; slot[t] = slot[ixj]; slot[ixj] = sv;
                }
            }
            __syncthreads();
        }
    }

    // gather payload in sorted order
    if (t < n) {
        int sv = slot[t];
        bx[t] = cls_box[c * CAP + sv];
        cf[t] = cls_conf[c * CAP + sv];
    }

    // greedy NMS: bitmask find-first + single parallel IoU pass per pick
    int cur = -1;
    const int nw = (n + 31) >> 5;
    while (true) {
        __syncthreads();   // publish bitmask updates / payload
        if (t == 0) {
            int nxt = -1;
            int start = cur + 1;
            if (start < n) {
                int w = start >> 5;
                unsigned m = words[w] & (0xFFFFFFFFu << (start & 31));
                while (true) {
                    if (m) { nxt = (w << 5) + __ffs(m) - 1; break; }
                    if (++w >= nw) break;
                    m = words[w];
                }
            }
            s_cur = nxt;
        }
        __syncthreads();
        cur = s_cur;
        if (cur < 0) break;

        float4 curb = bx[cur];
        float a1 = (curb.z - curb.x + 1.0f) * (curb.w - curb.y + 1.0f);
        int j = cur + 1 + t;
        if (j < n) {
            if ((words[j >> 5] >> (j & 31)) & 1u) {
                float4 b = bx[j];
                float xx1 = fmaxf(curb.x, b.x);
                float yy1 = fmaxf(curb.y, b.y);
                float xx2 = fminf(curb.z, b.z);
                float yy2 = fminf(curb.w, b.w);
                float iw = xx2 - xx1 + 1.0f;
                float ih = yy2 - yy1 + 1.0f;
                float inter = fmaxf(iw, 0.0f) * fmaxf(ih, 0.0f);
                float a2 = (b.z - b.x + 1.0f) * (b.w - b.y + 1.0f);
                float iou = inter / (a1 + a2 - inter + 1e-16f);
                if (iou > 0.4f)   // NMS_THRES
                    atomicAnd(&words[j >> 5], ~(1u << (j & 31)));
            }
        }
        if (t == 0) {
            int pp = atomicAdd(pool_count, 1);
            if (pp < POOL) {
                unsigned long long lk = key[cur];
                // repack: (~score)<<31 | orig_idx(18b)<<13 | pool_idx(13b)
                pool_key[pp] = ((lk >> 32) << 31) | ((lk & 0xFFFFFFFFull) << 13) |
                               (unsigned long long)pp;
                pool_conf[pp] = cf[cur];
                pool_cls[pp] = c;
            }
        }
    }
}

// ---------------- stage4: global top-300 by score-key, then conf re-sort, output
__global__ __launch_bounds__(1024) void k_final(const unsigned long long* __restrict__ pool_key,
                                                const float* __restrict__ pool_conf,
                                                const int* __restrict__ pool_cls,
                                                const int* __restrict__ pool_count,
                                                float* __restrict__ out) {
    __shared__ unsigned long long skey[POOL];  // 64 KB
    const int t = threadIdx.x;
    const int K = min(*pool_count, POOL);
    for (int i = t; i < POOL; i += 1024) skey[i] = (i < K) ? pool_key[i] : ~0ULL;
    __syncthreads();

    int P = 512;
    while (P < K) P <<= 1;  // runtime-sized bitonic, P >= 512 > 300
    for (int k = 2; k <= P; k <<= 1) {
        for (int j = k >> 1; j > 0; j >>= 1) {
            for (int i = t; i < P; i += 1024) {
                int ixj = i ^ j;
                if (ixj > i) {
                    unsigned long long a = skey[i], b = skey[ixj];
                    if ((a > b) == ((i & k) == 0)) { skey[i] = b; skey[ixj] = a; }
                }
            }
            __syncthreads();
        }
    }

    // slot s = s-th global pick. Final order: conf desc, ties slot desc
    // (= reversed stable ascending argsort of the reference)
    const int M = min(K, 300);
    unsigned long long k2 = ~0ULL;
    unsigned cb = 0;
    int mycls = 0;
    if (t < M) {
        int pidx = (int)(skey[t] & 0x1FFFull);
        float cfv = pool_conf[pidx];
        mycls = pool_cls[pidx];
        cb = __float_as_uint(cfv);
        k2 = ((unsigned long long)(~cb) << 32) | (unsigned)(~t);
    }
    __syncthreads();
    if (t < 512) skey[t] = k2;  // t in [M,512) pads with ~0ULL
    if (t < M) {
        skey[1024 + t] = cb;
        skey[2048 + t] = (unsigned long long)(unsigned)mycls;
    }
    __syncthreads();
    for (int k = 2; k <= 512; k <<= 1) {
        for (int j = k >> 1; j > 0; j >>= 1) {
            for (int i = t; i < 512; i += 1024) {
                int ixj = i ^ j;
                if (ixj > i) {
                    unsigned long long a = skey[i], b = skey[ixj];
                    if ((a > b) == ((i & k) == 0)) { skey[i] = b; skey[ixj] = a; }
                }
            }
            __syncthreads();
        }
    }

    if (t < 300) {
        float idv = 0.0f, pv = 0.0f;
        if (t < M) {  // all valid keys sort before ~0ULL padding
            unsigned long long kk = skey[t];
            int slotv = (int)(~(unsigned)(kk & 0xFFFFFFFFull));
            pv = __uint_as_float((unsigned)skey[1024 + slotv]);
            idv = (float)(int)skey[2048 + slotv];
        }
        out[t] = idv;        // ids (1,300)
        out[300 + t] = pv;   // probs (300,)
    }
}

extern "C" void kernel_launch(void* const* d_in, const int* in_sizes, int n_in,
                              void* d_out, int out_size, void* d_ws, size_t ws_size,
                              hipStream_t stream) {
    const float4* det4 = (const float4*)d_in[0];
    float* out = (float*)d_out;
    char* ws = (char*)d_ws;

    // workspace layout (~2.4 MB total)
    int* cls_count = (int*)(ws);                      // 80 * 4
    int* pool_count = (int*)(ws + 384);               // 4
    float* cls_score = (float*)(ws + 512);            // 80*1024*4 = 327680
    int* cls_idx = (int*)(ws + 512 + 327680);         // 327680
    float* cls_conf = (float*)(ws + 512 + 655360);    // 327680
    float4* cls_box = (float4*)(ws + 983552);         // 80*1024*16 = 1310720 (16B aligned)
    unsigned long long* pool_key = (unsigned long long*)(ws + 2294272);  // 8192*8
    float* pool_conf = (float*)(ws + 2359808);        // 8192*4
    int* pool_cls = (int*)(ws + 2392576);             // 8192*4

    k_init<<<1, 128, 0, stream>>>(cls_count, pool_count);
    k_stage1<<<NBOX / TBOX, 256, 0, stream>>>(det4, cls_score, cls_idx, cls_conf,
                                              cls_box, cls_count);
    k_nms<<<NCLS, 1024, 0, stream>>>(cls_score, cls_idx, cls_conf, cls_box, cls_count,
                                     pool_key, pool_conf, pool_cls, pool_count);
    k_final<<<1, 1024, 0, stream>>>(pool_key, pool_conf, pool_cls, pool_count, out);
}